// Round 1
// baseline (830.573 us; speedup 1.0000x reference)
//
#include <hip/hip_runtime.h>

#define S_LEN  2048
#define HIDDEN 512
#define NHEAD  8
#define DHEAD  64
#define NSEL   256
#define QB     4
#define SCALE_ 0.125f

// monotone float->uint mapping (ascending float == ascending uint)
__device__ __forceinline__ unsigned mapu(float f) {
  unsigned u = __float_as_uint(f);
  return (u & 0x80000000u) ? ~u : (u | 0x80000000u);
}

// C[m][n] = sum_k A[m][k] * B[n][k]   (A: MxK, B: NxK, both row-major)
__global__ __launch_bounds__(256) void gemm_nt(const float* __restrict__ A,
                                               const float* __restrict__ B,
                                               float* __restrict__ C,
                                               int M, int N, int K) {
  __shared__ float As[64][33];   // +1 pad: 2-way conflicts max (free)
  __shared__ float Bs[32][65];   // transposed tile, +1 pad
  const int m0 = blockIdx.x * 64, n0 = blockIdx.y * 64;
  const int t  = threadIdx.x;
  const int tx = t & 15, ty = t >> 4;
  float acc[4][4] = {};
  for (int k0 = 0; k0 < K; k0 += 32) {
    __syncthreads();
#pragma unroll
    for (int s = 0; s < 2; ++s) {
      int slot = t + s * 256;
      int r = slot >> 3, c = (slot & 7) << 2;
      const float4 fa = *(const float4*)&A[(size_t)(m0 + r) * K + k0 + c];
      As[r][c + 0] = fa.x; As[r][c + 1] = fa.y; As[r][c + 2] = fa.z; As[r][c + 3] = fa.w;
      const float4 fb = *(const float4*)&B[(size_t)(n0 + r) * K + k0 + c];
      Bs[c + 0][r] = fb.x; Bs[c + 1][r] = fb.y; Bs[c + 2][r] = fb.z; Bs[c + 3][r] = fb.w;
    }
    __syncthreads();
#pragma unroll
    for (int kk = 0; kk < 32; ++kk) {
      float a[4], b[4];
#pragma unroll
      for (int i = 0; i < 4; ++i) a[i] = As[ty * 4 + i][kk];
#pragma unroll
      for (int j = 0; j < 4; ++j) b[j] = Bs[kk][tx * 4 + j];
#pragma unroll
      for (int i = 0; i < 4; ++i)
#pragma unroll
        for (int j = 0; j < 4; ++j) acc[i][j] += a[i] * b[j];
    }
  }
#pragma unroll
  for (int i = 0; i < 4; ++i) {
    float4 o = make_float4(acc[i][0], acc[i][1], acc[i][2], acc[i][3]);
    *(float4*)&C[(size_t)(m0 + ty * 4 + i) * N + n0 + tx * 4] = o;
  }
}

// One block = 4 waves = 4 query rows of head h (h = bid%8 for XCD/L2 affinity).
__global__ __launch_bounds__(256) void fasa_attn(const float* __restrict__ Q,
                                                 const float* __restrict__ K,
                                                 const float* __restrict__ V,
                                                 float* __restrict__ O) {
  __shared__ float    qs[QB][DHEAD];       // 1 KB
  __shared__ float    imp[QB][S_LEN];      // 32 KB
  __shared__ unsigned hist[QB][256];       // 4 KB
  __shared__ int      sel[QB][NSEL];       // 4 KB
  __shared__ float    wbuf[QB][NSEL];      // 4 KB
  __shared__ int      eqbuf[QB][64];       // 1 KB
  __shared__ unsigned cnt[QB], eqcnt[QB];
  __shared__ unsigned rstate[QB][2];

  const int bid  = blockIdx.x;
  const int h    = bid & (NHEAD - 1);
  const int qb   = bid >> 3;
  const int t    = threadIdx.x;
  const int wv   = t >> 6;        // wave id == local query row
  const int lane = t & 63;
  const int row0 = qb * QB;

  {
    int r = t >> 6, d = t & 63;
    qs[r][d] = Q[(size_t)(row0 + r) * HIDDEN + h * DHEAD + d];
  }
  if (lane == 0) { cnt[wv] = 0; eqcnt[wv] = 0; }
  __syncthreads();

  // ---- phase 1: importance = dot over dims [0,32) for all 2048 keys ----
  const float* Kh = K + h * DHEAD;
  for (int ks = 0; ks < S_LEN / 256; ++ks) {
    const int key = ks * 256 + t;
    const float* krow = &Kh[(size_t)key * HIDDEN];
    float a0 = 0.f, a1 = 0.f, a2 = 0.f, a3 = 0.f;
#pragma unroll
    for (int k4 = 0; k4 < 8; ++k4) {
      const float4 kf = *(const float4*)&krow[k4 * 4];
      const float4 q0 = *(const float4*)&qs[0][k4 * 4];
      const float4 q1 = *(const float4*)&qs[1][k4 * 4];
      const float4 q2 = *(const float4*)&qs[2][k4 * 4];
      const float4 q3 = *(const float4*)&qs[3][k4 * 4];
      a0 += kf.x*q0.x + kf.y*q0.y + kf.z*q0.z + kf.w*q0.w;
      a1 += kf.x*q1.x + kf.y*q1.y + kf.z*q1.z + kf.w*q1.w;
      a2 += kf.x*q2.x + kf.y*q2.y + kf.z*q2.z + kf.w*q2.w;
      a3 += kf.x*q3.x + kf.y*q3.y + kf.z*q3.z + kf.w*q3.w;
    }
    imp[0][key] = a0; imp[1][key] = a1; imp[2][key] = a2; imp[3][key] = a3;
  }
  __syncthreads();

  // ---- phase 2: exact top-256 threshold via 4-round radix on bytes ----
  unsigned prefix = 0;
  unsigned krem   = NSEL;
#pragma unroll 1
  for (int b = 3; b >= 0; --b) {
    for (int i = lane; i < 256; i += 64) hist[wv][i] = 0;
    __syncthreads();
    const int shift = b * 8;
    for (int i = lane; i < S_LEN; i += 64) {
      unsigned u = mapu(imp[wv][i]);
      bool ok = (b == 3) || ((u >> (shift + 8)) == prefix);
      if (ok) atomicAdd(&hist[wv][(u >> shift) & 0xFF], 1u);
    }
    __syncthreads();
    // wave-parallel suffix scan over 256 bins (descending); lane -> group 63-lane
    const int g = 63 - lane;
    unsigned c0 = hist[wv][4*g+0], c1 = hist[wv][4*g+1];
    unsigned c2 = hist[wv][4*g+2], c3 = hist[wv][4*g+3];
    unsigned lsum = c0 + c1 + c2 + c3;
    unsigned incl = lsum;
#pragma unroll
    for (int off = 1; off < 64; off <<= 1) {
      unsigned o = __shfl_up(incl, off);
      if (lane >= off) incl += o;
    }
    const unsigned excl = incl - lsum;                 // count in bins strictly above my group
    const unsigned ab3 = excl, ab2 = excl + c3, ab1 = excl + c3 + c2, ab0 = excl + c3 + c2 + c1;
    if (ab3 < krem && krem <= ab3 + c3) { rstate[wv][0] = 4u*g+3u; rstate[wv][1] = krem - ab3; }
    if (ab2 < krem && krem <= ab2 + c2) { rstate[wv][0] = 4u*g+2u; rstate[wv][1] = krem - ab2; }
    if (ab1 < krem && krem <= ab1 + c1) { rstate[wv][0] = 4u*g+1u; rstate[wv][1] = krem - ab1; }
    if (ab0 < krem && krem <= ab0 + c0) { rstate[wv][0] = 4u*g+0u; rstate[wv][1] = krem - ab0; }
    __syncthreads();
    prefix = (prefix << 8) | rstate[wv][0];
    krem   = rstate[wv][1];
    __syncthreads();
  }
  const unsigned T = prefix;   // exact bits of the 256th-largest importance

  // ---- collect indices: all > T, then lowest-index ties == T ----
  for (int i = lane; i < S_LEN; i += 64) {
    unsigned u = mapu(imp[wv][i]);
    if (u > T)       { unsigned p = atomicAdd(&cnt[wv], 1u);   sel[wv][p] = i; }
    else if (u == T) { unsigned p = atomicAdd(&eqcnt[wv], 1u); if (p < 64) eqbuf[wv][p] = i; }
  }
  __syncthreads();
  const unsigned ngt  = cnt[wv];
  const unsigned need = NSEL - ngt;
  const unsigned ne   = eqcnt[wv];
  if (ne == need && ne <= 64) {
    for (unsigned j = lane; j < ne; j += 64) sel[wv][ngt + j] = eqbuf[wv][j];
  } else if (lane == 0) {
    if (ne <= 64) {                      // rare: sort ties ascending, take lowest `need`
      for (unsigned a2 = 1; a2 < ne; ++a2) {
        int kv2 = eqbuf[wv][a2]; int bp = (int)a2;
        while (bp > 0 && eqbuf[wv][bp-1] > kv2) { eqbuf[wv][bp] = eqbuf[wv][bp-1]; --bp; }
        eqbuf[wv][bp] = kv2;
      }
      for (unsigned j = 0; j < need; ++j) sel[wv][ngt + j] = eqbuf[wv][j];
    } else {                             // pathological: serial ascending scan
      unsigned taken = 0;
      for (int i = 0; i < S_LEN && taken < need; ++i)
        if (mapu(imp[wv][i]) == T) { sel[wv][ngt + taken] = i; ++taken; }
    }
  }
  __syncthreads();

  // ---- phase 3: full scores on selected keys, softmax, PV ----
  int sidx[4];
#pragma unroll
  for (int m = 0; m < 4; ++m) sidx[m] = sel[wv][lane * 4 + m];
  float sc[4];
#pragma unroll
  for (int m = 0; m < 4; ++m) {
    const float* kr = &Kh[(size_t)sidx[m] * HIDDEN];
    float s = 0.f;
#pragma unroll
    for (int k4 = 0; k4 < 16; ++k4) {
      const float4 kf = *(const float4*)&kr[k4 * 4];
      const float4 qv = *(const float4*)&qs[wv][k4 * 4];
      s += kf.x*qv.x + kf.y*qv.y + kf.z*qv.z + kf.w*qv.w;
    }
    sc[m] = s * SCALE_;
  }
  float mx = -1e30f;
#pragma unroll
  for (int m = 0; m < 4; ++m) mx = fmaxf(mx, sc[m]);
#pragma unroll
  for (int off = 32; off; off >>= 1) mx = fmaxf(mx, __shfl_xor(mx, off));
  float zs = 0.f;
#pragma unroll
  for (int m = 0; m < 4; ++m) { sc[m] = expf(sc[m] - mx); zs += sc[m]; }
#pragma unroll
  for (int off = 32; off; off >>= 1) zs += __shfl_xor(zs, off);
#pragma unroll
  for (int m = 0; m < 4; ++m) wbuf[wv][lane * 4 + m] = sc[m];
  const float rz = 1.0f / zs;
  __syncthreads();

  const float* Vh = V + h * DHEAD;
  float outv = 0.f;
#pragma unroll 8
  for (int j = 0; j < NSEL; ++j) {
    const int idx = sel[wv][j];
    outv += wbuf[wv][j] * Vh[(size_t)idx * HIDDEN + lane];   // coalesced: lane = d
  }
  O[(size_t)(row0 + wv) * HIDDEN + h * DHEAD + lane] = outv * rz;
}

extern "C" void kernel_launch(void* const* d_in, const int* in_sizes, int n_in,
                              void* d_out, int out_size, void* d_ws, size_t ws_size,
                              hipStream_t stream) {
  const float* x  = (const float*)d_in[0];
  const float* wq = (const float*)d_in[1];
  const float* wk = (const float*)d_in[2];
  const float* wv = (const float*)d_in[3];
  const float* wo = (const float*)d_in[4];
  float* out = (float*)d_out;

  // workspace: Q,K,V,AO each 2048*512 fp32 = 4 MB -> 16 MB total
  float* Qb = (float*)d_ws;
  float* Kb = Qb + (size_t)S_LEN * HIDDEN;
  float* Vb = Kb + (size_t)S_LEN * HIDDEN;
  float* AO = Vb + (size_t)S_LEN * HIDDEN;

  dim3 g(S_LEN / 64, HIDDEN / 64);
  gemm_nt<<<g, 256, 0, stream>>>(x, wq, Qb, S_LEN, HIDDEN, HIDDEN);
  gemm_nt<<<g, 256, 0, stream>>>(x, wk, Kb, S_LEN, HIDDEN, HIDDEN);
  gemm_nt<<<g, 256, 0, stream>>>(x, wv, Vb, S_LEN, HIDDEN, HIDDEN);
  fasa_attn<<<dim3(NHEAD * (S_LEN / QB)), 256, 0, stream>>>(Qb, Kb, Vb, AO);
  gemm_nt<<<g, 256, 0, stream>>>(AO, wo, out, S_LEN, HIDDEN, HIDDEN);
}

// Round 2
// 753.987 us; speedup vs baseline: 1.1016x; 1.1016x over previous
//
#include <hip/hip_runtime.h>

#define S_LEN  2048
#define HIDDEN 512
#define NHEAD  8
#define DHEAD  64
#define NSEL   256
#define ROWS_A 8
#define SCALE_ 0.125f

// intra-wave LDS producer->consumer sync (lockstep lanes + drain LDS queue)
#define WAVE_SYNC() __asm__ volatile("s_waitcnt lgkmcnt(0)" ::: "memory")

// monotone float->uint mapping (ascending float == ascending uint)
__device__ __forceinline__ unsigned mapu(float f) {
  unsigned u = __float_as_uint(f);
  return (u & 0x80000000u) ? ~u : (u | 0x80000000u);
}

// C[m][n] = sum_k A[m][k] * B[n][k]   (A: MxK, B: NxK, row-major)
__global__ __launch_bounds__(256) void gemm_nt(const float* __restrict__ A,
                                               const float* __restrict__ B,
                                               float* __restrict__ C,
                                               int M, int N, int K) {
  __shared__ float As[32][68];   // [k][m], stride 68 floats: 16B-aligned rows, conflict-light
  __shared__ float Bs[32][68];   // [k][n]
  const int m0 = blockIdx.x * 64, n0 = blockIdx.y * 64;
  const int t  = threadIdx.x;
  const int tx = t & 15, ty = t >> 4;
  float acc[4][4] = {};
  for (int k0 = 0; k0 < K; k0 += 32) {
    __syncthreads();
#pragma unroll
    for (int s = 0; s < 2; ++s) {
      int slot = t + s * 256;
      int r = slot >> 3, c = (slot & 7) << 2;
      const float4 fa = *(const float4*)&A[(size_t)(m0 + r) * K + k0 + c];
      As[c + 0][r] = fa.x; As[c + 1][r] = fa.y; As[c + 2][r] = fa.z; As[c + 3][r] = fa.w;
      const float4 fb = *(const float4*)&B[(size_t)(n0 + r) * K + k0 + c];
      Bs[c + 0][r] = fb.x; Bs[c + 1][r] = fb.y; Bs[c + 2][r] = fb.z; Bs[c + 3][r] = fb.w;
    }
    __syncthreads();
#pragma unroll
    for (int kk = 0; kk < 32; ++kk) {
      const float4 a4 = *(const float4*)&As[kk][ty * 4];   // ds_read_b128, broadcast over tx
      const float4 b4 = *(const float4*)&Bs[kk][tx * 4];   // ds_read_b128
      const float a[4] = {a4.x, a4.y, a4.z, a4.w};
      const float b[4] = {b4.x, b4.y, b4.z, b4.w};
#pragma unroll
      for (int i = 0; i < 4; ++i)
#pragma unroll
        for (int j = 0; j < 4; ++j) acc[i][j] += a[i] * b[j];
    }
  }
#pragma unroll
  for (int i = 0; i < 4; ++i) {
    float4 o = make_float4(acc[i][0], acc[i][1], acc[i][2], acc[i][3]);
    *(float4*)&C[(size_t)(m0 + ty * 4 + i) * N + n0 + tx * 4] = o;
  }
}

// Block = 512 threads = 8 waves = 8 query rows of head h (h = bid&7: XCD/L2 affinity).
// Cooperative importance (phase 1, one barrier), then fully wave-private radix select.
__global__ __launch_bounds__(512, 4) void fasa_select(const float* __restrict__ Q,
                                                      const float* __restrict__ K,
                                                      unsigned short* __restrict__ selg) {
  __shared__ float    qs[ROWS_A][32];        // 1 KB   (only dominant dims 0..31)
  __shared__ unsigned impu[ROWS_A][S_LEN];   // 64 KB  (mapu(importance), stored once)
  __shared__ unsigned hist[ROWS_A][256];     // 8 KB
  __shared__ unsigned short eqbuf[ROWS_A][64];
  __shared__ unsigned cnt[ROWS_A], eqcnt[ROWS_A];
  __shared__ unsigned rstate[ROWS_A][2];

  const int bid  = blockIdx.x;
  const int h    = bid & (NHEAD - 1);
  const int qb   = bid >> 3;
  const int row0 = qb * ROWS_A;
  const int t    = threadIdx.x;
  const int wv   = t >> 6, lane = t & 63;

  if (t < ROWS_A * 32) {
    int r = t >> 5, d = t & 31;
    qs[r][d] = Q[(size_t)(row0 + r) * HIDDEN + h * DHEAD + d];
  }
  __syncthreads();

  // ---- phase 1: imp = dot over dims [0,32) for all keys; 4 keys/thread, 8 rows ----
  const float* Kh = K + h * DHEAD;
  {
    float acc[ROWS_A][4] = {};
#pragma unroll
    for (int k4 = 0; k4 < 8; ++k4) {
      float4 kf[4];
#pragma unroll
      for (int m = 0; m < 4; ++m)
        kf[m] = *(const float4*)&Kh[(size_t)(m * 512 + t) * HIDDEN + k4 * 4];
#pragma unroll
      for (int r = 0; r < ROWS_A; ++r) {
        const float4 qv = *(const float4*)&qs[r][k4 * 4];   // LDS broadcast
#pragma unroll
        for (int m = 0; m < 4; ++m)
          acc[r][m] += kf[m].x * qv.x + kf[m].y * qv.y + kf[m].z * qv.z + kf[m].w * qv.w;
      }
    }
#pragma unroll
    for (int r = 0; r < ROWS_A; ++r)
#pragma unroll
      for (int m = 0; m < 4; ++m)
        impu[r][m * 512 + t] = mapu(acc[r][m]);
  }
  __syncthreads();   // the only cross-wave dependency

  // ---- phase 2 (wave-private): exact top-256 threshold, 4-round byte radix ----
  unsigned prefix = 0, krem = NSEL;
#pragma unroll 1
  for (int b = 3; b >= 0; --b) {
    hist[wv][lane] = 0; hist[wv][lane + 64] = 0; hist[wv][lane + 128] = 0; hist[wv][lane + 192] = 0;
    WAVE_SYNC();
    const int shift = b * 8;
#pragma unroll 1
    for (int j = 0; j < 8; ++j) {
      const uint4 u4 = *(const uint4*)&impu[wv][j * 256 + lane * 4];
      const unsigned uu[4] = {u4.x, u4.y, u4.z, u4.w};
#pragma unroll
      for (int e = 0; e < 4; ++e) {
        const unsigned u = uu[e];
        const bool ok = (b == 3) || ((u >> (shift + 8)) == prefix);
        if (ok) atomicAdd(&hist[wv][(u >> shift) & 0xFF], 1u);
      }
    }
    WAVE_SYNC();
    // wave-parallel suffix scan over 256 bins (descending value order)
    const int g = 63 - lane;
    const uint4 c4 = *(const uint4*)&hist[wv][4 * g];
    const unsigned c0 = c4.x, c1 = c4.y, c2 = c4.z, c3 = c4.w;
    const unsigned lsum = c0 + c1 + c2 + c3;
    unsigned incl = lsum;
#pragma unroll
    for (int off = 1; off < 64; off <<= 1) {
      unsigned o = __shfl_up(incl, off);
      if (lane >= off) incl += o;
    }
    const unsigned excl = incl - lsum;
    const unsigned ab3 = excl, ab2 = excl + c3, ab1 = excl + c3 + c2, ab0 = excl + c3 + c2 + c1;
    if (ab3 < krem && krem <= ab3 + c3) { rstate[wv][0] = 4u*g+3u; rstate[wv][1] = krem - ab3; }
    if (ab2 < krem && krem <= ab2 + c2) { rstate[wv][0] = 4u*g+2u; rstate[wv][1] = krem - ab2; }
    if (ab1 < krem && krem <= ab1 + c1) { rstate[wv][0] = 4u*g+1u; rstate[wv][1] = krem - ab1; }
    if (ab0 < krem && krem <= ab0 + c0) { rstate[wv][0] = 4u*g+0u; rstate[wv][1] = krem - ab0; }
    WAVE_SYNC();
    prefix = (prefix << 8) | rstate[wv][0];
    krem   = rstate[wv][1];
  }
  const unsigned T = prefix;   // exact bits of the 256th-largest importance

  // ---- collect: all > T straight to global; lowest-index ties == T fill the rest ----
  if (lane == 0) { cnt[wv] = 0; eqcnt[wv] = 0; }
  WAVE_SYNC();
  unsigned short* srow = selg + ((size_t)(h * S_LEN) + row0 + wv) * NSEL;
#pragma unroll 1
  for (int j = 0; j < 8; ++j) {
    const uint4 u4 = *(const uint4*)&impu[wv][j * 256 + lane * 4];
    const unsigned uu[4] = {u4.x, u4.y, u4.z, u4.w};
#pragma unroll
    for (int e = 0; e < 4; ++e) {
      const unsigned u = uu[e];
      const int i = j * 256 + lane * 4 + e;
      if (u > T)       { unsigned p = atomicAdd(&cnt[wv], 1u);   srow[p] = (unsigned short)i; }
      else if (u == T) { unsigned p = atomicAdd(&eqcnt[wv], 1u); if (p < 64) eqbuf[wv][p] = (unsigned short)i; }
    }
  }
  WAVE_SYNC();
  const unsigned ngt = cnt[wv], ne = eqcnt[wv];
  const unsigned need = NSEL - ngt;
  if (ne == need && ne <= 64) {
    for (unsigned j = lane; j < ne; j += 64) srow[ngt + j] = eqbuf[wv][j];
  } else if (lane == 0) {
    if (ne <= 64) {                       // rare: sort ties ascending, keep lowest `need`
      for (unsigned a = 1; a < ne; ++a) {
        unsigned short kv = eqbuf[wv][a]; int bp = (int)a;
        while (bp > 0 && eqbuf[wv][bp - 1] > kv) { eqbuf[wv][bp] = eqbuf[wv][bp - 1]; --bp; }
        eqbuf[wv][bp] = kv;
      }
      for (unsigned j = 0; j < need; ++j) srow[ngt + j] = eqbuf[wv][j];
    } else {                              // pathological: serial ascending scan
      unsigned taken = 0;
      for (int i = 0; i < S_LEN && taken < need; ++i)
        if (impu[wv][i] == T) { srow[ngt + taken] = (unsigned short)i; ++taken; }
    }
  }
}

// Block = 256 threads = 4 waves = 4 query rows; fully wave-private, zero barriers.
__global__ __launch_bounds__(256, 4) void fasa_attend(const float* __restrict__ Q,
                                                      const float* __restrict__ K,
                                                      const float* __restrict__ V,
                                                      const unsigned short* __restrict__ selg,
                                                      float* __restrict__ O) {
  __shared__ float qs[4][DHEAD];     // 1 KB
  __shared__ float wbuf[4][NSEL];    // 4 KB
  __shared__ int   ibuf[4][NSEL];    // 4 KB
  const int bid = blockIdx.x;
  const int h   = bid & (NHEAD - 1);
  const int qb  = bid >> 3;
  const int t   = threadIdx.x, wv = t >> 6, lane = t & 63;
  const int row = qb * 4 + wv;

  qs[wv][lane] = Q[(size_t)row * HIDDEN + h * DHEAD + lane];
  const unsigned short* srow = selg + ((size_t)(h * S_LEN) + row) * NSEL;
  const ushort4 s4 = *(const ushort4*)&srow[lane * 4];
  int sidx[4] = {(int)s4.x, (int)s4.y, (int)s4.z, (int)s4.w};
  WAVE_SYNC();   // qs visible to whole wave

  // scores over selected keys: lane owns 4 keys, reads their K rows (L1-friendly)
  const float* Kh = K + h * DHEAD;
  float sc[4] = {0.f, 0.f, 0.f, 0.f};
#pragma unroll
  for (int k4 = 0; k4 < 16; ++k4) {
    const float4 qv = *(const float4*)&qs[wv][k4 * 4];   // broadcast
#pragma unroll
    for (int m = 0; m < 4; ++m) {
      const float4 kf = *(const float4*)&Kh[(size_t)sidx[m] * HIDDEN + k4 * 4];
      sc[m] += kf.x * qv.x + kf.y * qv.y + kf.z * qv.z + kf.w * qv.w;
    }
  }
#pragma unroll
  for (int m = 0; m < 4; ++m) sc[m] *= SCALE_;

  float mx = fmaxf(fmaxf(sc[0], sc[1]), fmaxf(sc[2], sc[3]));
#pragma unroll
  for (int off = 32; off; off >>= 1) mx = fmaxf(mx, __shfl_xor(mx, off));
  float zs = 0.f;
#pragma unroll
  for (int m = 0; m < 4; ++m) { sc[m] = expf(sc[m] - mx); zs += sc[m]; }
#pragma unroll
  for (int off = 32; off; off >>= 1) zs += __shfl_xor(zs, off);
  const float rz = 1.0f / zs;

  *(float4*)&wbuf[wv][lane * 4] = make_float4(sc[0], sc[1], sc[2], sc[3]);
  *(int4*)&ibuf[wv][lane * 4]   = make_int4(sidx[0], sidx[1], sidx[2], sidx[3]);
  WAVE_SYNC();

  const float* Vh = V + h * DHEAD;
  float outv = 0.f;
#pragma unroll 4
  for (int j = 0; j < NSEL; j += 4) {
    const int4   id4 = *(const int4*)&ibuf[wv][j];     // broadcast
    const float4 w4  = *(const float4*)&wbuf[wv][j];   // broadcast
    outv += w4.x * Vh[(size_t)id4.x * HIDDEN + lane];  // coalesced 256B per wave
    outv += w4.y * Vh[(size_t)id4.y * HIDDEN + lane];
    outv += w4.z * Vh[(size_t)id4.z * HIDDEN + lane];
    outv += w4.w * Vh[(size_t)id4.w * HIDDEN + lane];
  }
  O[(size_t)row * HIDDEN + h * DHEAD + lane] = outv * rz;
}

extern "C" void kernel_launch(void* const* d_in, const int* in_sizes, int n_in,
                              void* d_out, int out_size, void* d_ws, size_t ws_size,
                              hipStream_t stream) {
  const float* x  = (const float*)d_in[0];
  const float* wq = (const float*)d_in[1];
  const float* wk = (const float*)d_in[2];
  const float* wv = (const float*)d_in[3];
  const float* wo = (const float*)d_in[4];
  float* out = (float*)d_out;

  // ws: Q,K,V,AO 4 MB each + sel (u16, 16384x256 = 8 MB) -> 24 MB
  float* Qb = (float*)d_ws;
  float* Kb = Qb + (size_t)S_LEN * HIDDEN;
  float* Vb = Kb + (size_t)S_LEN * HIDDEN;
  float* AO = Vb + (size_t)S_LEN * HIDDEN;
  unsigned short* selg = (unsigned short*)(AO + (size_t)S_LEN * HIDDEN);

  dim3 g(S_LEN / 64, HIDDEN / 64);
  gemm_nt<<<g, 256, 0, stream>>>(x, wq, Qb, S_LEN, HIDDEN, HIDDEN);
  gemm_nt<<<g, 256, 0, stream>>>(x, wk, Kb, S_LEN, HIDDEN, HIDDEN);
  gemm_nt<<<g, 256, 0, stream>>>(x, wv, Vb, S_LEN, HIDDEN, HIDDEN);
  fasa_select<<<dim3((S_LEN / ROWS_A) * NHEAD), 512, 0, stream>>>(Qb, Kb, selg);
  fasa_attend<<<dim3((S_LEN / 4) * NHEAD), 256, 0, stream>>>(Qb, Kb, Vb, selg, AO);
  gemm_nt<<<g, 256, 0, stream>>>(AO, wo, out, S_LEN, HIDDEN, HIDDEN);
}

// Round 3
// 497.605 us; speedup vs baseline: 1.6691x; 1.5152x over previous
//
#include <hip/hip_runtime.h>

#define S_LEN  2048
#define HIDDEN 512
#define NHEAD  8
#define DHEAD  64
#define NSEL   256
#define ROWS_A 8
#define SCALE_ 0.125f

// intra-wave LDS producer->consumer sync (lockstep lanes + drain LDS queue)
#define WAVE_SYNC() __asm__ volatile("s_waitcnt lgkmcnt(0)" ::: "memory")

// monotone float->uint mapping (ascending float == ascending uint)
__device__ __forceinline__ unsigned mapu(float f) {
  unsigned u = __float_as_uint(f);
  return (u & 0x80000000u) ? ~u : (u | 0x80000000u);
}

// C[m][n] = sum_k A[m][k] * B[n][k]   (A: MxK, B: NxK, row-major)
__global__ __launch_bounds__(256) void gemm_nt(const float* __restrict__ A,
                                               const float* __restrict__ B,
                                               float* __restrict__ C,
                                               int M, int N, int K) {
  __shared__ float As[32][68];   // [k][m]
  __shared__ float Bs[32][68];   // [k][n]
  const int m0 = blockIdx.x * 64, n0 = blockIdx.y * 64;
  const int t  = threadIdx.x;
  const int tx = t & 15, ty = t >> 4;
  float acc[4][4] = {};
  for (int k0 = 0; k0 < K; k0 += 32) {
    __syncthreads();
#pragma unroll
    for (int s = 0; s < 2; ++s) {
      int slot = t + s * 256;
      int r = slot >> 3, c = (slot & 7) << 2;
      const float4 fa = *(const float4*)&A[(size_t)(m0 + r) * K + k0 + c];
      As[c + 0][r] = fa.x; As[c + 1][r] = fa.y; As[c + 2][r] = fa.z; As[c + 3][r] = fa.w;
      const float4 fb = *(const float4*)&B[(size_t)(n0 + r) * K + k0 + c];
      Bs[c + 0][r] = fb.x; Bs[c + 1][r] = fb.y; Bs[c + 2][r] = fb.z; Bs[c + 3][r] = fb.w;
    }
    __syncthreads();
#pragma unroll
    for (int kk = 0; kk < 32; ++kk) {
      const float4 a4 = *(const float4*)&As[kk][ty * 4];
      const float4 b4 = *(const float4*)&Bs[kk][tx * 4];
      const float a[4] = {a4.x, a4.y, a4.z, a4.w};
      const float b[4] = {b4.x, b4.y, b4.z, b4.w};
#pragma unroll
      for (int i = 0; i < 4; ++i)
#pragma unroll
        for (int j = 0; j < 4; ++j) acc[i][j] += a[i] * b[j];
    }
  }
#pragma unroll
  for (int i = 0; i < 4; ++i) {
    float4 o = make_float4(acc[i][0], acc[i][1], acc[i][2], acc[i][3]);
    *(float4*)&C[(size_t)(m0 + ty * 4 + i) * N + n0 + tx * 4] = o;
  }
}

// importance GEMM: impu[h*S + q][k] = mapu( sum_{d<32} Q[q][h*64+d] * K[k][h*64+d] )
// 64x64 tile per block, K-depth 32 (single step), fully coalesced in/out.
__global__ __launch_bounds__(256) void imp_gemm(const float* __restrict__ Q,
                                                const float* __restrict__ K,
                                                unsigned* __restrict__ impu) {
  __shared__ float Qs[32][68];   // [d][q]
  __shared__ float Ks[32][68];   // [d][k]
  const int bid  = blockIdx.x;
  const int h    = bid & (NHEAD - 1);      // h = XCD affinity
  const int tile = bid >> 3;
  const int q0   = (tile & 31) * 64;
  const int k0   = (tile >> 5) * 64;
  const int t  = threadIdx.x;
  const int tx = t & 15, ty = t >> 4;
#pragma unroll
  for (int s = 0; s < 2; ++s) {
    int slot = t + s * 256;
    int r = slot >> 3, c = (slot & 7) << 2;
    const float4 fq = *(const float4*)&Q[(size_t)(q0 + r) * HIDDEN + h * DHEAD + c];
    Qs[c + 0][r] = fq.x; Qs[c + 1][r] = fq.y; Qs[c + 2][r] = fq.z; Qs[c + 3][r] = fq.w;
    const float4 fk = *(const float4*)&K[(size_t)(k0 + r) * HIDDEN + h * DHEAD + c];
    Ks[c + 0][r] = fk.x; Ks[c + 1][r] = fk.y; Ks[c + 2][r] = fk.z; Ks[c + 3][r] = fk.w;
  }
  __syncthreads();
  float acc[4][4] = {};
#pragma unroll
  for (int d = 0; d < 32; ++d) {
    const float4 a4 = *(const float4*)&Qs[d][ty * 4];
    const float4 b4 = *(const float4*)&Ks[d][tx * 4];
    const float a[4] = {a4.x, a4.y, a4.z, a4.w};
    const float b[4] = {b4.x, b4.y, b4.z, b4.w};
#pragma unroll
    for (int i = 0; i < 4; ++i)
#pragma unroll
      for (int j = 0; j < 4; ++j) acc[i][j] += a[i] * b[j];
  }
#pragma unroll
  for (int i = 0; i < 4; ++i) {
    uint4 o = make_uint4(mapu(acc[i][0]), mapu(acc[i][1]), mapu(acc[i][2]), mapu(acc[i][3]));
    *(uint4*)&impu[((size_t)(h * S_LEN) + q0 + ty * 4 + i) * S_LEN + k0 + tx * 4] = o;
  }
}

// One wave per query row: row's 2048 impu values live in 32 VGPRs/lane.
// 4-pass radix from registers; sel written via LDS buffer -> coalesced uint4.
__global__ __launch_bounds__(512) void radix_select(const unsigned* __restrict__ impu,
                                                    unsigned short* __restrict__ selg) {
  __shared__ unsigned hist[ROWS_A][256];          // 8 KB
  __shared__ unsigned short selbuf[ROWS_A][NSEL]; // 4 KB
  __shared__ unsigned short eqbuf[ROWS_A][64];    // 1 KB
  __shared__ unsigned cnt[ROWS_A], eqcnt[ROWS_A];
  __shared__ unsigned rstate[ROWS_A][2];

  const int t = threadIdx.x, wv = t >> 6, lane = t & 63;
  const size_t gr = (size_t)blockIdx.x * ROWS_A + wv;   // global row = h*S + q
  const unsigned* rowp = impu + gr * S_LEN;

  uint4 u[8];
#pragma unroll
  for (int j = 0; j < 8; ++j) u[j] = *(const uint4*)&rowp[j * 256 + lane * 4];

  unsigned prefix = 0, krem = NSEL;
#pragma unroll 1
  for (int b = 3; b >= 0; --b) {
    hist[wv][lane] = 0; hist[wv][lane + 64] = 0; hist[wv][lane + 128] = 0; hist[wv][lane + 192] = 0;
    WAVE_SYNC();
    const int shift = b * 8;
#pragma unroll
    for (int j = 0; j < 8; ++j) {
      const unsigned uu[4] = {u[j].x, u[j].y, u[j].z, u[j].w};
#pragma unroll
      for (int e = 0; e < 4; ++e) {
        const unsigned v = uu[e];
        const bool ok = (b == 3) || ((v >> (shift + 8)) == prefix);
        if (ok) atomicAdd(&hist[wv][(v >> shift) & 0xFF], 1u);
      }
    }
    WAVE_SYNC();
    const int g = 63 - lane;
    const uint4 c4 = *(const uint4*)&hist[wv][4 * g];
    const unsigned c0 = c4.x, c1 = c4.y, c2 = c4.z, c3 = c4.w;
    const unsigned lsum = c0 + c1 + c2 + c3;
    unsigned incl = lsum;
#pragma unroll
    for (int off = 1; off < 64; off <<= 1) {
      unsigned o = __shfl_up(incl, off);
      if (lane >= off) incl += o;
    }
    const unsigned excl = incl - lsum;
    const unsigned ab3 = excl, ab2 = excl + c3, ab1 = excl + c3 + c2, ab0 = excl + c3 + c2 + c1;
    if (ab3 < krem && krem <= ab3 + c3) { rstate[wv][0] = 4u*g+3u; rstate[wv][1] = krem - ab3; }
    if (ab2 < krem && krem <= ab2 + c2) { rstate[wv][0] = 4u*g+2u; rstate[wv][1] = krem - ab2; }
    if (ab1 < krem && krem <= ab1 + c1) { rstate[wv][0] = 4u*g+1u; rstate[wv][1] = krem - ab1; }
    if (ab0 < krem && krem <= ab0 + c0) { rstate[wv][0] = 4u*g+0u; rstate[wv][1] = krem - ab0; }
    WAVE_SYNC();
    prefix = (prefix << 8) | rstate[wv][0];
    krem   = rstate[wv][1];
  }
  const unsigned T = prefix;

  if (lane == 0) { cnt[wv] = 0; eqcnt[wv] = 0; }
  WAVE_SYNC();
#pragma unroll
  for (int j = 0; j < 8; ++j) {
    const unsigned uu[4] = {u[j].x, u[j].y, u[j].z, u[j].w};
#pragma unroll
    for (int e = 0; e < 4; ++e) {
      const unsigned v = uu[e];
      const int i = j * 256 + lane * 4 + e;
      if (v > T)       { unsigned p = atomicAdd(&cnt[wv], 1u);   selbuf[wv][p] = (unsigned short)i; }
      else if (v == T) { unsigned p = atomicAdd(&eqcnt[wv], 1u); if (p < 64) eqbuf[wv][p] = (unsigned short)i; }
    }
  }
  WAVE_SYNC();
  const unsigned ngt = cnt[wv], ne = eqcnt[wv];
  const unsigned need = NSEL - ngt;
  if (ne == need && ne <= 64) {
    for (unsigned j = lane; j < ne; j += 64) selbuf[wv][ngt + j] = eqbuf[wv][j];
  } else if (lane == 0) {
    if (ne <= 64) {                       // rare: sort ties ascending, keep lowest `need`
      for (unsigned a = 1; a < ne; ++a) {
        unsigned short kv = eqbuf[wv][a]; int bp = (int)a;
        while (bp > 0 && eqbuf[wv][bp - 1] > kv) { eqbuf[wv][bp] = eqbuf[wv][bp - 1]; --bp; }
        eqbuf[wv][bp] = kv;
      }
      for (unsigned j = 0; j < need; ++j) selbuf[wv][ngt + j] = eqbuf[wv][j];
    } else {                              // pathological: serial ascending scan (global re-read)
      unsigned taken = 0;
      for (int i = 0; i < S_LEN && taken < need; ++i)
        if (rowp[i] == T) { selbuf[wv][ngt + taken] = (unsigned short)i; ++taken; }
    }
  }
  WAVE_SYNC();
  if (lane < 32) {   // coalesced copy-out: 32 lanes x 16B = 512B row
    const uint4 o = *(const uint4*)&selbuf[wv][lane * 8];
    *(uint4*)&selg[gr * NSEL + lane * 8] = o;
  }
}

// ===== validated round-2 fused select: fallback when ws too small =====
__global__ __launch_bounds__(512, 4) void fasa_select(const float* __restrict__ Q,
                                                      const float* __restrict__ K,
                                                      unsigned short* __restrict__ selg) {
  __shared__ float    qs[ROWS_A][32];
  __shared__ unsigned impu[ROWS_A][S_LEN];
  __shared__ unsigned hist[ROWS_A][256];
  __shared__ unsigned short eqbuf[ROWS_A][64];
  __shared__ unsigned cnt[ROWS_A], eqcnt[ROWS_A];
  __shared__ unsigned rstate[ROWS_A][2];

  const int bid  = blockIdx.x;
  const int h    = bid & (NHEAD - 1);
  const int qb   = bid >> 3;
  const int row0 = qb * ROWS_A;
  const int t    = threadIdx.x;
  const int wv   = t >> 6, lane = t & 63;

  if (t < ROWS_A * 32) {
    int r = t >> 5, d = t & 31;
    qs[r][d] = Q[(size_t)(row0 + r) * HIDDEN + h * DHEAD + d];
  }
  __syncthreads();

  const float* Kh = K + h * DHEAD;
  {
    float acc[ROWS_A][4] = {};
#pragma unroll
    for (int k4 = 0; k4 < 8; ++k4) {
      float4 kf[4];
#pragma unroll
      for (int m = 0; m < 4; ++m)
        kf[m] = *(const float4*)&Kh[(size_t)(m * 512 + t) * HIDDEN + k4 * 4];
#pragma unroll
      for (int r = 0; r < ROWS_A; ++r) {
        const float4 qv = *(const float4*)&qs[r][k4 * 4];
#pragma unroll
        for (int m = 0; m < 4; ++m)
          acc[r][m] += kf[m].x * qv.x + kf[m].y * qv.y + kf[m].z * qv.z + kf[m].w * qv.w;
      }
    }
#pragma unroll
    for (int r = 0; r < ROWS_A; ++r)
#pragma unroll
      for (int m = 0; m < 4; ++m)
        impu[r][m * 512 + t] = mapu(acc[r][m]);
  }
  __syncthreads();

  unsigned prefix = 0, krem = NSEL;
#pragma unroll 1
  for (int b = 3; b >= 0; --b) {
    hist[wv][lane] = 0; hist[wv][lane + 64] = 0; hist[wv][lane + 128] = 0; hist[wv][lane + 192] = 0;
    WAVE_SYNC();
    const int shift = b * 8;
#pragma unroll 1
    for (int j = 0; j < 8; ++j) {
      const uint4 u4 = *(const uint4*)&impu[wv][j * 256 + lane * 4];
      const unsigned uu[4] = {u4.x, u4.y, u4.z, u4.w};
#pragma unroll
      for (int e = 0; e < 4; ++e) {
        const unsigned u = uu[e];
        const bool ok = (b == 3) || ((u >> (shift + 8)) == prefix);
        if (ok) atomicAdd(&hist[wv][(u >> shift) & 0xFF], 1u);
      }
    }
    WAVE_SYNC();
    const int g = 63 - lane;
    const uint4 c4 = *(const uint4*)&hist[wv][4 * g];
    const unsigned c0 = c4.x, c1 = c4.y, c2 = c4.z, c3 = c4.w;
    const unsigned lsum = c0 + c1 + c2 + c3;
    unsigned incl = lsum;
#pragma unroll
    for (int off = 1; off < 64; off <<= 1) {
      unsigned o = __shfl_up(incl, off);
      if (lane >= off) incl += o;
    }
    const unsigned excl = incl - lsum;
    const unsigned ab3 = excl, ab2 = excl + c3, ab1 = excl + c3 + c2, ab0 = excl + c3 + c2 + c1;
    if (ab3 < krem && krem <= ab3 + c3) { rstate[wv][0] = 4u*g+3u; rstate[wv][1] = krem - ab3; }
    if (ab2 < krem && krem <= ab2 + c2) { rstate[wv][0] = 4u*g+2u; rstate[wv][1] = krem - ab2; }
    if (ab1 < krem && krem <= ab1 + c1) { rstate[wv][0] = 4u*g+1u; rstate[wv][1] = krem - ab1; }
    if (ab0 < krem && krem <= ab0 + c0) { rstate[wv][0] = 4u*g+0u; rstate[wv][1] = krem - ab0; }
    WAVE_SYNC();
    prefix = (prefix << 8) | rstate[wv][0];
    krem   = rstate[wv][1];
  }
  const unsigned T = prefix;

  if (lane == 0) { cnt[wv] = 0; eqcnt[wv] = 0; }
  WAVE_SYNC();
  unsigned short* srow = selg + ((size_t)(h * S_LEN) + row0 + wv) * NSEL;
#pragma unroll 1
  for (int j = 0; j < 8; ++j) {
    const uint4 u4 = *(const uint4*)&impu[wv][j * 256 + lane * 4];
    const unsigned uu[4] = {u4.x, u4.y, u4.z, u4.w};
#pragma unroll
    for (int e = 0; e < 4; ++e) {
      const unsigned u = uu[e];
      const int i = j * 256 + lane * 4 + e;
      if (u > T)       { unsigned p = atomicAdd(&cnt[wv], 1u);   srow[p] = (unsigned short)i; }
      else if (u == T) { unsigned p = atomicAdd(&eqcnt[wv], 1u); if (p < 64) eqbuf[wv][p] = (unsigned short)i; }
    }
  }
  WAVE_SYNC();
  const unsigned ngt = cnt[wv], ne = eqcnt[wv];
  const unsigned need = NSEL - ngt;
  if (ne == need && ne <= 64) {
    for (unsigned j = lane; j < ne; j += 64) srow[ngt + j] = eqbuf[wv][j];
  } else if (lane == 0) {
    if (ne <= 64) {
      for (unsigned a = 1; a < ne; ++a) {
        unsigned short kv = eqbuf[wv][a]; int bp = (int)a;
        while (bp > 0 && eqbuf[wv][bp - 1] > kv) { eqbuf[wv][bp] = eqbuf[wv][bp - 1]; --bp; }
        eqbuf[wv][bp] = kv;
      }
      for (unsigned j = 0; j < need; ++j) srow[ngt + j] = eqbuf[wv][j];
    } else {
      unsigned taken = 0;
      for (int i = 0; i < S_LEN && taken < need; ++i)
        if (impu[wv][i] == T) { srow[ngt + taken] = (unsigned short)i; ++taken; }
    }
  }
}

// Block = 256 threads = 4 waves = 4 query rows; fully wave-private, zero barriers.
__global__ __launch_bounds__(256, 4) void fasa_attend(const float* __restrict__ Q,
                                                      const float* __restrict__ K,
                                                      const float* __restrict__ V,
                                                      const unsigned short* __restrict__ selg,
                                                      float* __restrict__ O) {
  __shared__ float qs[4][DHEAD];
  __shared__ float wbuf[4][NSEL];
  __shared__ int   ibuf[4][NSEL];
  const int bid = blockIdx.x;
  const int h   = bid & (NHEAD - 1);
  const int qb  = bid >> 3;
  const int t   = threadIdx.x, wv = t >> 6, lane = t & 63;
  const int row = qb * 4 + wv;

  qs[wv][lane] = Q[(size_t)row * HIDDEN + h * DHEAD + lane];
  const unsigned short* srow = selg + ((size_t)(h * S_LEN) + row) * NSEL;
  const ushort4 s4 = *(const ushort4*)&srow[lane * 4];
  int sidx[4] = {(int)s4.x, (int)s4.y, (int)s4.z, (int)s4.w};
  WAVE_SYNC();

  const float* Kh = K + h * DHEAD;
  float sc[4] = {0.f, 0.f, 0.f, 0.f};
#pragma unroll
  for (int k4 = 0; k4 < 16; ++k4) {
    const float4 qv = *(const float4*)&qs[wv][k4 * 4];
#pragma unroll
    for (int m = 0; m < 4; ++m) {
      const float4 kf = *(const float4*)&Kh[(size_t)sidx[m] * HIDDEN + k4 * 4];
      sc[m] += kf.x * qv.x + kf.y * qv.y + kf.z * qv.z + kf.w * qv.w;
    }
  }
#pragma unroll
  for (int m = 0; m < 4; ++m) sc[m] *= SCALE_;

  float mx = fmaxf(fmaxf(sc[0], sc[1]), fmaxf(sc[2], sc[3]));
#pragma unroll
  for (int off = 32; off; off >>= 1) mx = fmaxf(mx, __shfl_xor(mx, off));
  float zs = 0.f;
#pragma unroll
  for (int m = 0; m < 4; ++m) { sc[m] = expf(sc[m] - mx); zs += sc[m]; }
#pragma unroll
  for (int off = 32; off; off >>= 1) zs += __shfl_xor(zs, off);
  const float rz = 1.0f / zs;

  *(float4*)&wbuf[wv][lane * 4] = make_float4(sc[0], sc[1], sc[2], sc[3]);
  *(int4*)&ibuf[wv][lane * 4]   = make_int4(sidx[0], sidx[1], sidx[2], sidx[3]);
  WAVE_SYNC();

  const float* Vh = V + h * DHEAD;
  float outv = 0.f;
#pragma unroll 4
  for (int j = 0; j < NSEL; j += 4) {
    const int4   id4 = *(const int4*)&ibuf[wv][j];
    const float4 w4  = *(const float4*)&wbuf[wv][j];
    outv += w4.x * Vh[(size_t)id4.x * HIDDEN + lane];
    outv += w4.y * Vh[(size_t)id4.y * HIDDEN + lane];
    outv += w4.z * Vh[(size_t)id4.z * HIDDEN + lane];
    outv += w4.w * Vh[(size_t)id4.w * HIDDEN + lane];
  }
  O[(size_t)row * HIDDEN + h * DHEAD + lane] = outv * rz;
}

extern "C" void kernel_launch(void* const* d_in, const int* in_sizes, int n_in,
                              void* d_out, int out_size, void* d_ws, size_t ws_size,
                              hipStream_t stream) {
  const float* x  = (const float*)d_in[0];
  const float* wq = (const float*)d_in[1];
  const float* wk = (const float*)d_in[2];
  const float* wv = (const float*)d_in[3];
  const float* wo = (const float*)d_in[4];
  float* out = (float*)d_out;

  // ws: Q,K,V,AO 4 MB each + selg 8 MB + impu 128 MB = 152 MB
  float* Qb = (float*)d_ws;
  float* Kb = Qb + (size_t)S_LEN * HIDDEN;
  float* Vb = Kb + (size_t)S_LEN * HIDDEN;
  float* AO = Vb + (size_t)S_LEN * HIDDEN;
  unsigned short* selg = (unsigned short*)(AO + (size_t)S_LEN * HIDDEN);
  unsigned* impu = (unsigned*)(selg + (size_t)NHEAD * S_LEN * NSEL);

  const size_t need = (size_t)4 * S_LEN * HIDDEN * 4          // Q,K,V,AO
                    + (size_t)NHEAD * S_LEN * NSEL * 2        // selg
                    + (size_t)NHEAD * S_LEN * S_LEN * 4;      // impu

  dim3 g(S_LEN / 64, HIDDEN / 64);
  gemm_nt<<<g, 256, 0, stream>>>(x, wq, Qb, S_LEN, HIDDEN, HIDDEN);
  gemm_nt<<<g, 256, 0, stream>>>(x, wk, Kb, S_LEN, HIDDEN, HIDDEN);
  gemm_nt<<<g, 256, 0, stream>>>(x, wv, Vb, S_LEN, HIDDEN, HIDDEN);
  if (ws_size >= need) {
    imp_gemm<<<dim3(NHEAD * 32 * 32), 256, 0, stream>>>(Qb, Kb, impu);
    radix_select<<<dim3(NHEAD * S_LEN / ROWS_A), 512, 0, stream>>>(impu, selg);
  } else {
    fasa_select<<<dim3((S_LEN / ROWS_A) * NHEAD), 512, 0, stream>>>(Qb, Kb, selg);
  }
  fasa_attend<<<dim3((S_LEN / 4) * NHEAD), 256, 0, stream>>>(Qb, Kb, Vb, selg, AO);
  gemm_nt<<<g, 256, 0, stream>>>(AO, wo, out, S_LEN, HIDDEN, HIDDEN);
}